// Round 3
// baseline (3475.072 us; speedup 1.0000x reference)
//
#include <hip/hip_runtime.h>

#define NN 100000
#define EE 1600000
#define CC 128
#define NP 100032   // padded to 64-row tiles (1563 * 64)
#define NBK 782     // dst buckets of 128 nodes (782*128 = 100096 >= NN)
#define BCAP 2304   // bucket capacity: E/NBK=2046 expected, +5.6 sigma slack

typedef _Float16 f16;
typedef __attribute__((ext_vector_type(2))) f16 f16x2;
typedef __attribute__((ext_vector_type(4))) f16 f16x4;
typedef __attribute__((ext_vector_type(8))) f16 f16x8;
typedef __attribute__((ext_vector_type(4))) float f32x4;

#define MFMA16(a, b, c) __builtin_amdgcn_mfma_f32_16x16x32_f16(a, b, c, 0, 0, 0)

// x / agg live in SLAB layout: [8 slabs of 16ch][NP rows][16 ch] fp16.
// element (row, ch) at ((ch>>4)*NP + row)*16 + (ch&15).
// Aggregate blocks are slab-pinned (slab = blockIdx&7 -> XCD via round-robin
// dispatch): per-XCD gather working set = 3.2 MB < 4 MB L2. (Confirmed round 2:
// FETCH 257->40 MB.)

// ---- phase 1: partition edges into dst-buckets; rank saved from 1st pass ----
__global__ __launch_bounds__(1024) void k_part(const int* __restrict__ src,
                                               const int* __restrict__ dst,
                                               int* __restrict__ bcur,
                                               unsigned* __restrict__ bedge) {
  __shared__ int hist[NBK];
  __shared__ int base[NBK];
  const int t = threadIdx.x;
  for (int i = t; i < NBK; i += 1024) hist[i] = 0;
  __syncthreads();
  const int4* src4 = (const int4*)src;
  const int4* dst4 = (const int4*)dst;
  int4 s[4], d[4];
  int rk[16];
  bool val[4];
#pragma unroll
  for (int w = 0; w < 4; w++) {
    int i4 = blockIdx.x * 4096 + w * 1024 + t;
    val[w] = (i4 < EE / 4);
    if (val[w]) {
      s[w] = src4[i4];
      d[w] = dst4[i4];
      rk[w * 4 + 0] = atomicAdd(&hist[d[w].x >> 7], 1);
      rk[w * 4 + 1] = atomicAdd(&hist[d[w].y >> 7], 1);
      rk[w * 4 + 2] = atomicAdd(&hist[d[w].z >> 7], 1);
      rk[w * 4 + 3] = atomicAdd(&hist[d[w].w >> 7], 1);
    }
  }
  __syncthreads();
  for (int i = t; i < NBK; i += 1024) {
    int c = hist[i];
    base[i] = c ? atomicAdd(&bcur[i], c) : 0;
  }
  __syncthreads();
#pragma unroll
  for (int w = 0; w < 4; w++) {
    if (val[w]) {
      int ss[4] = {s[w].x, s[w].y, s[w].z, s[w].w};
      int dd[4] = {d[w].x, d[w].y, d[w].z, d[w].w};
#pragma unroll
      for (int q = 0; q < 4; q++) {
        int b = dd[q] >> 7;
        int slot = base[b] + rk[w * 4 + q];
        if (slot < BCAP)
          bedge[(size_t)b * BCAP + slot] =
              (unsigned)ss[q] | ((unsigned)(dd[q] & 127) << 17);
      }
    }
  }
}

// ---- bucket-count exclusive scan (one block) -> bbase, off[NN] -------------
__global__ __launch_bounds__(1024) void k_bscan(const int* __restrict__ bcur,
                                                int* __restrict__ bbase,
                                                int* __restrict__ off) {
  __shared__ int sh[1024];
  int t = threadIdx.x;
  int v = (t < NBK) ? min(bcur[t], BCAP) : 0;
  sh[t] = v;
  __syncthreads();
  for (int d = 1; d < 1024; d <<= 1) {
    int a = (t >= d) ? sh[t - d] : 0;
    __syncthreads();
    sh[t] += a;
    __syncthreads();
  }
  if (t < NBK) bbase[t] = sh[t] - v;  // exclusive
  if (t == 1023) off[NN] = sh[1023];  // total (== kept edges)
}

// ---- per-bucket: hist -> node offsets (off) -> CSR fill --------------------
__global__ __launch_bounds__(256) void k_bfill2(const int* __restrict__ bcur,
                                                const int* __restrict__ bbase,
                                                const unsigned* __restrict__ bedge,
                                                int* __restrict__ off,
                                                int* __restrict__ csr) {
  __shared__ int h[128];
  __shared__ int sc[128];
  __shared__ int curs[128];
  const int b = blockIdx.x;
  const int t = threadIdx.x;
  if (t < 128) h[t] = 0;
  __syncthreads();
  const int cnt = min(bcur[b], BCAP);
  const unsigned* be = bedge + (size_t)b * BCAP;
  for (int i = t; i < cnt; i += 256) atomicAdd(&h[(be[i] >> 17) & 127], 1);
  __syncthreads();
  int v = (t < 128) ? h[t] : 0;
  if (t < 128) sc[t] = v;
  __syncthreads();
  for (int d = 1; d < 128; d <<= 1) {
    int a = (t >= d && t < 128) ? sc[t - d] : 0;
    __syncthreads();
    if (t < 128) sc[t] += a;
    __syncthreads();
  }
  if (t < 128) {
    int o = bbase[b] + sc[t] - v;  // exclusive node offset
    int n = b * 128 + t;
    if (n < NN) off[n] = o;
    curs[t] = o;
  }
  __syncthreads();
  for (int i = t; i < cnt; i += 256) {
    unsigned u = be[i];
    int node = (u >> 17) & 127;
    int p = atomicAdd(&curs[node], 1);
    csr[p] = (int)(u & 0x1FFFF);
  }
}

// ------- weight pack: fp32 [k][n] -> fp16 in MFMA B-fragment order ----------
struct WPtrs { const float* w[9]; };
__global__ __launch_bounds__(256) void k_packw(WPtrs wp, f16* __restrict__ out) {
  int t = blockIdx.x * 256 + threadIdx.x;  // 9 * 16384
  int mat = t >> 14;
  int idx = t & 16383;
  int j = idx & 7;
  int lane = (idx >> 3) & 63;
  int ks = (idx >> 9) & 3;
  int nt = idx >> 11;
  int c16 = lane & 15, quad = lane >> 4;
  int k = ks * 32 + quad * 8 + j;
  int n = nt * 16 + c16;
  out[(size_t)mat * 16384 + idx] = (f16)wp.w[mat][k * CC + n];
}

// ---------------- layer-1 aggregate (Cin=3), 4-wide neighbor ILP ------------
__global__ __launch_bounds__(256) void k_agg3(const int* __restrict__ off,
                                              const int* __restrict__ csr,
                                              const float* __restrict__ pos,
                                              float* __restrict__ agg3) {
  int n = blockIdx.x * 256 + threadIdx.x;
  if (n >= NN) return;
  int b = off[n], e = off[n + 1];
  float a0 = 0.f, a1 = 0.f, a2 = 0.f;
  int i = b;
  for (; i + 4 <= e; i += 4) {
    int s0 = csr[i], s1 = csr[i + 1], s2 = csr[i + 2], s3 = csr[i + 3];
    float p00 = pos[s0 * 3 + 0], p01 = pos[s0 * 3 + 1], p02 = pos[s0 * 3 + 2];
    float p10 = pos[s1 * 3 + 0], p11 = pos[s1 * 3 + 1], p12 = pos[s1 * 3 + 2];
    float p20 = pos[s2 * 3 + 0], p21 = pos[s2 * 3 + 1], p22 = pos[s2 * 3 + 2];
    float p30 = pos[s3 * 3 + 0], p31 = pos[s3 * 3 + 1], p32 = pos[s3 * 3 + 2];
    a0 += (p00 + p10) + (p20 + p30);
    a1 += (p01 + p11) + (p21 + p31);
    a2 += (p02 + p12) + (p22 + p32);
  }
  for (; i < e; i++) {
    int s = csr[i];
    a0 += pos[s * 3 + 0];
    a1 += pos[s * 3 + 1];
    a2 += pos[s * 3 + 2];
  }
  float rd = 1.0f / fmaxf((float)(e - b), 1.0f);
  agg3[n * 3 + 0] = a0 * rd;
  agg3[n * 3 + 1] = a1 * rd;
  agg3[n * 3 + 2] = a2 * rd;
}

// ---------------- layer-1 node update (3 -> 128), slab-layout fp16 out ------
__global__ __launch_bounds__(256) void k_node1(
    const float* __restrict__ agg3, const float* __restrict__ pos,
    const float* __restrict__ wl, const float* __restrict__ bl,
    const float* __restrict__ wr, const float* __restrict__ g,
    const float* __restrict__ be, const float* __restrict__ bm,
    const float* __restrict__ bv, f16* __restrict__ x) {
  const int c = threadIdx.x & 127;
  const int np = threadIdx.x >> 7;  // node parity (uniform per wave)
  const float Wl0 = wl[c], Wl1 = wl[CC + c], Wl2 = wl[2 * CC + c];
  const float Wr0 = wr[c], Wr1 = wr[CC + c], Wr2 = wr[2 * CC + c];
  const float sc = g[c] * rsqrtf(bv[c] + 1e-5f);
  const float o0 = be[c] + (bl[c] - bm[c]) * sc;
  const size_t sb = ((size_t)(c >> 4) * NP) * 16 + (c & 15);  // slab base
  const int nbase = blockIdx.x * 256;
  const int nend = min(nbase + 256, NN);
#pragma unroll 4
  for (int n = nbase + np; n < nend; n += 2) {
    float acc = agg3[n * 3 + 0] * Wl0 + agg3[n * 3 + 1] * Wl1 +
                agg3[n * 3 + 2] * Wl2 + pos[n * 3 + 0] * Wr0 +
                pos[n * 3 + 1] * Wr1 + pos[n * 3 + 2] * Wr2;
    x[sb + (size_t)n * 16] = (f16)fmaxf(acc * sc + o0, 0.0f);
  }
}

// -------- aggregate via bucket + LDS atomics, slab-pinned to XCD ------------
// block = (bucket b, slab s); streams bedge[b] linearly (no off/csr dependent
// chain), gathers f16x4 from slab s (L2-resident), ds_add_f32 into
// acc[16ch][129pad] (per-edge 4 lanes -> 4 distinct banks).
__global__ __launch_bounds__(256) void k_agg_bucket(
    const int* __restrict__ bcur, const unsigned* __restrict__ bedge,
    const int* __restrict__ off, const f16* __restrict__ x,
    f16* __restrict__ agg) {
  const int slab = blockIdx.x & 7;
  const int b = blockIdx.x >> 3;
  const int t = threadIdx.x;
  __shared__ float acc[16][129];
  for (int i = t; i < 16 * 129; i += 256) ((float*)acc)[i] = 0.f;
  __syncthreads();
  const int cnt = min(bcur[b], BCAP);
  const unsigned* be = bedge + (size_t)b * BCAP;
  const int cl4 = (t & 3) * 4;
  const f16* xs = x + (size_t)slab * NP * 16 + cl4;
#pragma unroll 4
  for (int i = t >> 2; i < cnt; i += 64) {
    unsigned u = be[i];  // 4 lanes per edge share u (broadcast)
    int srcn = u & 0x1FFFF;
    int node = (u >> 17) & 127;
    f16x4 v = *(const f16x4*)(xs + (size_t)srcn * 16);
    atomicAdd(&acc[cl4 + 0][node], (float)v[0]);
    atomicAdd(&acc[cl4 + 1][node], (float)v[1]);
    atomicAdd(&acc[cl4 + 2][node], (float)v[2]);
    atomicAdd(&acc[cl4 + 3][node], (float)v[3]);
  }
  __syncthreads();
  const int node = t >> 1, half = t & 1;
  const int gid = b * 128 + node;
  if (gid < NN) {
    const int dg = off[gid + 1] - off[gid];
    const float rd = 1.0f / fmaxf((float)dg, 1.0f);
    f16x8 o;
#pragma unroll
    for (int j = 0; j < 8; j++) o[j] = (f16)(acc[half * 8 + j][node] * rd);
    *(f16x8*)(agg + ((size_t)slab * NP + gid) * 16 + half * 8) = o;
  }
}

// ---------------- SAGE MFMA fp16: D = agg@wl + x@wr, BN+ReLU ----------------
__global__ __launch_bounds__(256) void k_sage_mfma(
    const f16* __restrict__ xin, f16* __restrict__ xout,
    const f16* __restrict__ agg, const f16* __restrict__ wl,
    const f16* __restrict__ wr, const float* __restrict__ bl,
    const float* __restrict__ g, const float* __restrict__ be,
    const float* __restrict__ bm, const float* __restrict__ bv) {
  const int lane = threadIdx.x & 63;
  const int wave = threadIdx.x >> 6;
  const int c16 = lane & 15;
  const int quad = lane >> 4;
  const int n0 = blockIdx.x * 64 + wave * 16;
  const int rowX = n0 + c16;
  const int rowA = min(rowX, NN - 1);  // agg rows >= NN are never written
  f32x4 acc[8];
#pragma unroll
  for (int t = 0; t < 8; t++) acc[t] = {0.f, 0.f, 0.f, 0.f};
#pragma unroll
  for (int ks = 0; ks < 4; ks++) {
    const int cb = ks * 32 + quad * 8;  // channel base of this A-fragment
    const size_t sb = ((size_t)(cb >> 4) * NP) * 16 + (cb & 8);
    f16x8 Ax = *(const f16x8*)(xin + sb + (size_t)rowX * 16);
    f16x8 Aa = *(const f16x8*)(agg + sb + (size_t)rowA * 16);
#pragma unroll
    for (int nt = 0; nt < 8; nt++) {
      const size_t wo = (size_t)((nt * 4 + ks) * 64 + lane) * 8;
      f16x8 Bl = *(const f16x8*)(wl + wo);
      f16x8 Br = *(const f16x8*)(wr + wo);
      acc[nt] = MFMA16(Aa, Bl, acc[nt]);
      acc[nt] = MFMA16(Ax, Br, acc[nt]);
    }
  }
#pragma unroll
  for (int nt = 0; nt < 8; nt++) {
    const int col = nt * 16 + c16;
    const float blc = bl[col];
    const float sc = g[col] * rsqrtf(bv[col] + 1e-5f);
    const float mm = bm[col];
    const float bb = be[col];
#pragma unroll
    for (int r = 0; r < 4; r++) {
      const int node = n0 + quad * 4 + r;
      if (node < NN) {
        float yv = fmaxf((acc[nt][r] + blc - mm) * sc + bb, 0.0f);
        xout[((size_t)nt * NP + node) * 16 + c16] = (f16)yv;  // slab nt
      }
    }
  }
}

// -------- fused FC head: out = (relu(x@w1+b1)@w2+b2)@w3+b3, LDS relayout ----
__global__ __launch_bounds__(256) void k_dense_fused(
    const f16* __restrict__ x, const f16* __restrict__ w1,
    const f16* __restrict__ w2, const f16* __restrict__ w3,
    const float* __restrict__ b1, const float* __restrict__ b2,
    const float* __restrict__ b3, float* __restrict__ out) {
  const int lane = threadIdx.x & 63;
  const int wave = threadIdx.x >> 6;
  const int c16 = lane & 15;
  const int quad = lane >> 4;
  const int n0 = blockIdx.x * 64 + wave * 16;
  const int lrow = wave * 16;
  __shared__ f16 sh[64][136];  // +8 pad

  f32x4 acc[8];
#pragma unroll
  for (int t = 0; t < 8; t++) acc[t] = {0.f, 0.f, 0.f, 0.f};
  const int rowX = n0 + c16;
#pragma unroll
  for (int ks = 0; ks < 4; ks++) {
    const int cb = ks * 32 + quad * 8;
    const size_t sb = ((size_t)(cb >> 4) * NP) * 16 + (cb & 8);
    f16x8 Ax = *(const f16x8*)(x + sb + (size_t)rowX * 16);
#pragma unroll
    for (int nt = 0; nt < 8; nt++) {
      f16x8 B = *(const f16x8*)(w1 + (size_t)((nt * 4 + ks) * 64 + lane) * 8);
      acc[nt] = MFMA16(Ax, B, acc[nt]);
    }
  }
#pragma unroll
  for (int nt = 0; nt < 8; nt++) {
    const int col = nt * 16 + c16;
    const float bc = b1[col];
#pragma unroll
    for (int r = 0; r < 4; r++)
      sh[lrow + quad * 4 + r][col] = (f16)fmaxf(acc[nt][r] + bc, 0.0f);
  }
  // FC2 (wave-local rows, no barrier needed)
#pragma unroll
  for (int t = 0; t < 8; t++) acc[t] = {0.f, 0.f, 0.f, 0.f};
#pragma unroll
  for (int ks = 0; ks < 4; ks++) {
    f16x8 Ax = *(const f16x8*)&sh[lrow + c16][ks * 32 + quad * 8];
#pragma unroll
    for (int nt = 0; nt < 8; nt++) {
      f16x8 B = *(const f16x8*)(w2 + (size_t)((nt * 4 + ks) * 64 + lane) * 8);
      acc[nt] = MFMA16(Ax, B, acc[nt]);
    }
  }
#pragma unroll
  for (int nt = 0; nt < 8; nt++) {
    const int col = nt * 16 + c16;
    const float bc = b2[col];
#pragma unroll
    for (int r = 0; r < 4; r++)
      sh[lrow + quad * 4 + r][col] = (f16)(acc[nt][r] + bc);
  }
  // FC3 -> out (fp32)
#pragma unroll
  for (int t = 0; t < 8; t++) acc[t] = {0.f, 0.f, 0.f, 0.f};
#pragma unroll
  for (int ks = 0; ks < 4; ks++) {
    f16x8 Ax = *(const f16x8*)&sh[lrow + c16][ks * 32 + quad * 8];
#pragma unroll
    for (int nt = 0; nt < 8; nt++) {
      f16x8 B = *(const f16x8*)(w3 + (size_t)((nt * 4 + ks) * 64 + lane) * 8);
      acc[nt] = MFMA16(Ax, B, acc[nt]);
    }
  }
#pragma unroll
  for (int nt = 0; nt < 8; nt++) {
    const int col = nt * 16 + c16;
    const float bc = b3[col];
#pragma unroll
    for (int r = 0; r < 4; r++) {
      const int node = n0 + quad * 4 + r;
      if (node < NN) out[(size_t)node * CC + col] = acc[nt][r] + bc;
    }
  }
}

extern "C" void kernel_launch(void* const* d_in, const int* in_sizes, int n_in,
                              void* d_out, int out_size, void* d_ws,
                              size_t ws_size, hipStream_t stream) {
  const float* pos = (const float*)d_in[0];
  const int* ei = (const int*)d_in[1];
  const int* src = ei;
  const int* dst = ei + EE;
  auto P = [&](int i) { return (const float*)d_in[i]; };

  // ws: bcur[NBK] | bbase[NBK] | off[NN+2] | bedge[NBK*BCAP] | csr[E] |
  //     wp16 | xa | xb   (~66 MB)
  int* bcur = (int*)d_ws;
  int* bbase = bcur + NBK;
  int* off = bbase + NBK;
  unsigned* bedge = (unsigned*)(off + NN + 2);
  int* csr = (int*)(bedge + (size_t)NBK * BCAP);
  f16* wp16 = (f16*)(csr + EE);
  f16* xa = wp16 + 9 * 16384;
  f16* xb = xa + (size_t)NP * CC;

  f16* agg = (f16*)d_out;  // scratch until the final dense overwrites d_out

  hipMemsetAsync(bcur, 0, NBK * sizeof(int), stream);

  // CSR build: partition -> bucket scan -> per-bucket offsets+fill
  k_part<<<(EE / 4 + 4095) / 4096, 1024, 0, stream>>>(src, dst, bcur, bedge);
  k_bscan<<<1, 1024, 0, stream>>>(bcur, bbase, off);
  k_bfill2<<<NBK, 256, 0, stream>>>(bcur, bbase, bedge, off, csr);

  WPtrs wp;
  const int wsrc[9] = {9, 11, 16, 18, 23, 25, 30, 32, 34};
  for (int i = 0; i < 9; i++) wp.w[i] = P(wsrc[i]);
  k_packw<<<(9 * 16384) / 256, 256, 0, stream>>>(wp, wp16);

  // layer 1 (Cin=3): agg3 fp32 in d_out scratch (1.2 MB)
  k_agg3<<<(NN + 255) / 256, 256, 0, stream>>>(off, csr, pos, (float*)d_out);
  k_node1<<<(NN + 255) / 256, 256, 0, stream>>>(
      (const float*)d_out, pos, P(2), P(3), P(4), P(5), P(6), P(7), P(8), xa);

  const int NB = NP / 64;  // 1563
  // layers 2..4: ping-pong xa -> xb -> xa -> xb
  const f16* xi = xa;
  f16* xo = xb;
  for (int l = 1; l < 4; l++) {
    int base = 2 + 7 * l;
    int mat = (l - 1) * 2;
    k_agg_bucket<<<NBK * 8, 256, 0, stream>>>(bcur, bedge, off, xi, agg);
    k_sage_mfma<<<NB, 256, 0, stream>>>(xi, xo, agg,
                                        wp16 + (size_t)mat * 16384,
                                        wp16 + (size_t)(mat + 1) * 16384,
                                        P(base + 1), P(base + 3), P(base + 4),
                                        P(base + 5), P(base + 6));
    const f16* t = xi;
    xi = xo;
    xo = (f16*)t;
  }

  // fused FC head
  k_dense_fused<<<NB, 256, 0, stream>>>(xi, wp16 + (size_t)6 * 16384,
                                        wp16 + (size_t)7 * 16384,
                                        wp16 + (size_t)8 * 16384, P(31), P(33),
                                        P(35), (float*)d_out);
}

// Round 4
// 607.897 us; speedup vs baseline: 5.7165x; 5.7165x over previous
//
#include <hip/hip_runtime.h>

#define NN 100000
#define EE 1600000
#define CC 128
#define NP 100032   // padded to 64-row tiles (1563 * 64)
#define NBK 782     // dst buckets of 128 nodes (782*128 = 100096 >= NN)
#define BCAP 2304   // bucket capacity: E/NBK=2046 expected, +5.6 sigma slack

typedef _Float16 f16;
typedef __attribute__((ext_vector_type(2))) f16 f16x2;
typedef __attribute__((ext_vector_type(4))) f16 f16x4;
typedef __attribute__((ext_vector_type(8))) f16 f16x8;
typedef __attribute__((ext_vector_type(4))) float f32x4;

#define MFMA16(a, b, c) __builtin_amdgcn_mfma_f32_16x16x32_f16(a, b, c, 0, 0, 0)

// x / agg live in SLAB layout: [8 slabs of 16ch][NP rows][16 ch] fp16.
// element (row, ch) at ((ch>>4)*NP + row)*16 + (ch&15).
// Aggregate blocks are slab-pinned (slab = blockIdx&7 -> XCD via round-robin
// dispatch): per-XCD gather working set = 3.2 MB < 4 MB L2 (confirmed R2/R3:
// FETCH 257 -> ~41 MB). R3 lesson: NO LDS atomics on the edge path (50x).

// ---- phase 1: partition edges into dst-buckets; rank saved from 1st pass ----
__global__ __launch_bounds__(1024) void k_part(const int* __restrict__ src,
                                               const int* __restrict__ dst,
                                               int* __restrict__ bcur,
                                               unsigned* __restrict__ bedge) {
  __shared__ int hist[NBK];
  __shared__ int base[NBK];
  const int t = threadIdx.x;
  for (int i = t; i < NBK; i += 1024) hist[i] = 0;
  __syncthreads();
  const int4* src4 = (const int4*)src;
  const int4* dst4 = (const int4*)dst;
  int4 s[4], d[4];
  int rk[16];
  bool val[4];
#pragma unroll
  for (int w = 0; w < 4; w++) {
    int i4 = blockIdx.x * 4096 + w * 1024 + t;
    val[w] = (i4 < EE / 4);
    if (val[w]) {
      s[w] = src4[i4];
      d[w] = dst4[i4];
      rk[w * 4 + 0] = atomicAdd(&hist[d[w].x >> 7], 1);
      rk[w * 4 + 1] = atomicAdd(&hist[d[w].y >> 7], 1);
      rk[w * 4 + 2] = atomicAdd(&hist[d[w].z >> 7], 1);
      rk[w * 4 + 3] = atomicAdd(&hist[d[w].w >> 7], 1);
    }
  }
  __syncthreads();
  for (int i = t; i < NBK; i += 1024) {
    int c = hist[i];
    base[i] = c ? atomicAdd(&bcur[i], c) : 0;
  }
  __syncthreads();
#pragma unroll
  for (int w = 0; w < 4; w++) {
    if (val[w]) {
      int ss[4] = {s[w].x, s[w].y, s[w].z, s[w].w};
      int dd[4] = {d[w].x, d[w].y, d[w].z, d[w].w};
#pragma unroll
      for (int q = 0; q < 4; q++) {
        int b = dd[q] >> 7;
        int slot = base[b] + rk[w * 4 + q];
        if (slot < BCAP)
          bedge[(size_t)b * BCAP + slot] =
              (unsigned)ss[q] | ((unsigned)(dd[q] & 127) << 17);
      }
    }
  }
}

// ---- bucket-count exclusive scan (one block) -> bbase, off[NN] -------------
__global__ __launch_bounds__(1024) void k_bscan(const int* __restrict__ bcur,
                                                int* __restrict__ bbase,
                                                int* __restrict__ off) {
  __shared__ int sh[1024];
  int t = threadIdx.x;
  int v = (t < NBK) ? min(bcur[t], BCAP) : 0;
  sh[t] = v;
  __syncthreads();
  for (int d = 1; d < 1024; d <<= 1) {
    int a = (t >= d) ? sh[t - d] : 0;
    __syncthreads();
    sh[t] += a;
    __syncthreads();
  }
  if (t < NBK) bbase[t] = sh[t] - v;  // exclusive
  if (t == 1023) off[NN] = sh[1023];  // total (== kept edges)
}

// ---- per-bucket: hist -> node offsets (off) -> CSR fill --------------------
__global__ __launch_bounds__(256) void k_bfill2(const int* __restrict__ bcur,
                                                const int* __restrict__ bbase,
                                                const unsigned* __restrict__ bedge,
                                                int* __restrict__ off,
                                                int* __restrict__ csr) {
  __shared__ int h[128];
  __shared__ int sc[128];
  __shared__ int curs[128];
  const int b = blockIdx.x;
  const int t = threadIdx.x;
  if (t < 128) h[t] = 0;
  __syncthreads();
  const int cnt = min(bcur[b], BCAP);
  const unsigned* be = bedge + (size_t)b * BCAP;
  for (int i = t; i < cnt; i += 256) atomicAdd(&h[(be[i] >> 17) & 127], 1);
  __syncthreads();
  int v = (t < 128) ? h[t] : 0;
  if (t < 128) sc[t] = v;
  __syncthreads();
  for (int d = 1; d < 128; d <<= 1) {
    int a = (t >= d && t < 128) ? sc[t - d] : 0;
    __syncthreads();
    if (t < 128) sc[t] += a;
    __syncthreads();
  }
  if (t < 128) {
    int o = bbase[b] + sc[t] - v;  // exclusive node offset
    int n = b * 128 + t;
    if (n < NN) off[n] = o;
    curs[t] = o;
  }
  __syncthreads();
  for (int i = t; i < cnt; i += 256) {
    unsigned u = be[i];
    int node = (u >> 17) & 127;
    int p = atomicAdd(&curs[node], 1);
    csr[p] = (int)(u & 0x1FFFF);
  }
}

// ------- weight pack: fp32 [k][n] -> fp16 in MFMA B-fragment order ----------
struct WPtrs { const float* w[9]; };
__global__ __launch_bounds__(256) void k_packw(WPtrs wp, f16* __restrict__ out) {
  int t = blockIdx.x * 256 + threadIdx.x;  // 9 * 16384
  int mat = t >> 14;
  int idx = t & 16383;
  int j = idx & 7;
  int lane = (idx >> 3) & 63;
  int ks = (idx >> 9) & 3;
  int nt = idx >> 11;
  int c16 = lane & 15, quad = lane >> 4;
  int k = ks * 32 + quad * 8 + j;
  int n = nt * 16 + c16;
  out[(size_t)mat * 16384 + idx] = (f16)wp.w[mat][k * CC + n];
}

// ---------------- layer-1 aggregate (Cin=3), 4-wide neighbor ILP ------------
__global__ __launch_bounds__(256) void k_agg3(const int* __restrict__ off,
                                              const int* __restrict__ csr,
                                              const float* __restrict__ pos,
                                              float* __restrict__ agg3) {
  int n = blockIdx.x * 256 + threadIdx.x;
  if (n >= NN) return;
  int b = off[n], e = off[n + 1];
  float a0 = 0.f, a1 = 0.f, a2 = 0.f;
  int i = b;
  for (; i + 4 <= e; i += 4) {
    int s0 = csr[i], s1 = csr[i + 1], s2 = csr[i + 2], s3 = csr[i + 3];
    float p00 = pos[s0 * 3 + 0], p01 = pos[s0 * 3 + 1], p02 = pos[s0 * 3 + 2];
    float p10 = pos[s1 * 3 + 0], p11 = pos[s1 * 3 + 1], p12 = pos[s1 * 3 + 2];
    float p20 = pos[s2 * 3 + 0], p21 = pos[s2 * 3 + 1], p22 = pos[s2 * 3 + 2];
    float p30 = pos[s3 * 3 + 0], p31 = pos[s3 * 3 + 1], p32 = pos[s3 * 3 + 2];
    a0 += (p00 + p10) + (p20 + p30);
    a1 += (p01 + p11) + (p21 + p31);
    a2 += (p02 + p12) + (p22 + p32);
  }
  for (; i < e; i++) {
    int s = csr[i];
    a0 += pos[s * 3 + 0];
    a1 += pos[s * 3 + 1];
    a2 += pos[s * 3 + 2];
  }
  float rd = 1.0f / fmaxf((float)(e - b), 1.0f);
  agg3[n * 3 + 0] = a0 * rd;
  agg3[n * 3 + 1] = a1 * rd;
  agg3[n * 3 + 2] = a2 * rd;
}

// ---------------- layer-1 node update (3 -> 128), slab-layout fp16 out ------
__global__ __launch_bounds__(256) void k_node1(
    const float* __restrict__ agg3, const float* __restrict__ pos,
    const float* __restrict__ wl, const float* __restrict__ bl,
    const float* __restrict__ wr, const float* __restrict__ g,
    const float* __restrict__ be, const float* __restrict__ bm,
    const float* __restrict__ bv, f16* __restrict__ x) {
  const int c = threadIdx.x & 127;
  const int np = threadIdx.x >> 7;  // node parity (uniform per wave)
  const float Wl0 = wl[c], Wl1 = wl[CC + c], Wl2 = wl[2 * CC + c];
  const float Wr0 = wr[c], Wr1 = wr[CC + c], Wr2 = wr[2 * CC + c];
  const float sc = g[c] * rsqrtf(bv[c] + 1e-5f);
  const float o0 = be[c] + (bl[c] - bm[c]) * sc;
  const size_t sb = ((size_t)(c >> 4) * NP) * 16 + (c & 15);  // slab base
  const int nbase = blockIdx.x * 256;
  const int nend = min(nbase + 256, NN);
#pragma unroll 4
  for (int n = nbase + np; n < nend; n += 2) {
    float acc = agg3[n * 3 + 0] * Wl0 + agg3[n * 3 + 1] * Wl1 +
                agg3[n * 3 + 2] * Wl2 + pos[n * 3 + 0] * Wr0 +
                pos[n * 3 + 1] * Wr1 + pos[n * 3 + 2] * Wr2;
    x[sb + (size_t)n * 16] = (f16)fmaxf(acc * sc + o0, 0.0f);
  }
}

// -------- aggregate: quad-per-node over csr, slab-pinned, reg accum ---------
// block = 64 nodes x 4 lanes; slab = blockIdx&7 (-> XCD). Each lane owns one
// edge at a time, loads the full 16-ch slab row (2x f16x8 = 32B), accumulates
// in 16 f32 regs. csr index prefetched one iteration ahead. Quad shfl-reduce.
__global__ __launch_bounds__(256) void k_agg_quad(const int* __restrict__ off,
                                                  const int* __restrict__ csr,
                                                  const f16* __restrict__ x,
                                                  f16* __restrict__ agg) {
  const int slab = blockIdx.x & 7;
  const int n = (blockIdx.x >> 3) * 64 + (threadIdx.x >> 2);
  const int cl = threadIdx.x & 3;
  if (n >= NN) return;  // no barriers below; divergence safe
  const int b = off[n], e = off[n + 1];
  const f16* xs = x + (size_t)slab * NP * 16;
  float a[16];
#pragma unroll
  for (int j = 0; j < 16; j++) a[j] = 0.f;
  if (e > b) {
    int idx = csr[min(b + cl, e - 1)];
    for (int i = b; i < e; i += 4) {
      int idxn = 0;
      if (i + 4 < e) idxn = csr[min(i + 4 + cl, e - 1)];  // prefetch next
      const f16* p = xs + (size_t)idx * 16;
      f16x8 v0 = *(const f16x8*)(p);
      f16x8 v1 = *(const f16x8*)(p + 8);
      if (i + cl < e) {
#pragma unroll
        for (int j = 0; j < 8; j++) a[j] += (float)v0[j];
#pragma unroll
        for (int j = 0; j < 8; j++) a[8 + j] += (float)v1[j];
      }
      idx = idxn;
    }
  }
  // intra-quad reduce (xor 1, 2 stay within the quad)
#pragma unroll
  for (int j = 0; j < 16; j++) {
    a[j] += __shfl_xor(a[j], 1);
    a[j] += __shfl_xor(a[j], 2);
  }
  const float rd = 1.0f / fmaxf((float)(e - b), 1.0f);
  f16x4 o;
#pragma unroll
  for (int j = 0; j < 4; j++) o[j] = (f16)(a[cl * 4 + j] * rd);
  *(f16x4*)(agg + ((size_t)slab * NP + n) * 16 + cl * 4) = o;
}

// ---------------- SAGE MFMA fp16: D = agg@wl + x@wr, BN+ReLU ----------------
__global__ __launch_bounds__(256) void k_sage_mfma(
    const f16* __restrict__ xin, f16* __restrict__ xout,
    const f16* __restrict__ agg, const f16* __restrict__ wl,
    const f16* __restrict__ wr, const float* __restrict__ bl,
    const float* __restrict__ g, const float* __restrict__ be,
    const float* __restrict__ bm, const float* __restrict__ bv) {
  const int lane = threadIdx.x & 63;
  const int wave = threadIdx.x >> 6;
  const int c16 = lane & 15;
  const int quad = lane >> 4;
  const int n0 = blockIdx.x * 64 + wave * 16;
  const int rowX = n0 + c16;
  const int rowA = min(rowX, NN - 1);  // agg rows >= NN are never written
  f32x4 acc[8];
#pragma unroll
  for (int t = 0; t < 8; t++) acc[t] = {0.f, 0.f, 0.f, 0.f};
#pragma unroll
  for (int ks = 0; ks < 4; ks++) {
    const int cb = ks * 32 + quad * 8;  // channel base of this A-fragment
    const size_t sb = ((size_t)(cb >> 4) * NP) * 16 + (cb & 8);
    f16x8 Ax = *(const f16x8*)(xin + sb + (size_t)rowX * 16);
    f16x8 Aa = *(const f16x8*)(agg + sb + (size_t)rowA * 16);
#pragma unroll
    for (int nt = 0; nt < 8; nt++) {
      const size_t wo = (size_t)((nt * 4 + ks) * 64 + lane) * 8;
      f16x8 Bl = *(const f16x8*)(wl + wo);
      f16x8 Br = *(const f16x8*)(wr + wo);
      acc[nt] = MFMA16(Aa, Bl, acc[nt]);
      acc[nt] = MFMA16(Ax, Br, acc[nt]);
    }
  }
#pragma unroll
  for (int nt = 0; nt < 8; nt++) {
    const int col = nt * 16 + c16;
    const float blc = bl[col];
    const float sc = g[col] * rsqrtf(bv[col] + 1e-5f);
    const float mm = bm[col];
    const float bb = be[col];
#pragma unroll
    for (int r = 0; r < 4; r++) {
      const int node = n0 + quad * 4 + r;
      if (node < NN) {
        float yv = fmaxf((acc[nt][r] + blc - mm) * sc + bb, 0.0f);
        xout[((size_t)nt * NP + node) * 16 + c16] = (f16)yv;  // slab nt
      }
    }
  }
}

// -------- fused FC head: out = (relu(x@w1+b1)@w2+b2)@w3+b3, LDS relayout ----
__global__ __launch_bounds__(256) void k_dense_fused(
    const f16* __restrict__ x, const f16* __restrict__ w1,
    const f16* __restrict__ w2, const f16* __restrict__ w3,
    const float* __restrict__ b1, const float* __restrict__ b2,
    const float* __restrict__ b3, float* __restrict__ out) {
  const int lane = threadIdx.x & 63;
  const int wave = threadIdx.x >> 6;
  const int c16 = lane & 15;
  const int quad = lane >> 4;
  const int n0 = blockIdx.x * 64 + wave * 16;
  const int lrow = wave * 16;
  __shared__ f16 sh[64][136];  // +8 pad

  f32x4 acc[8];
#pragma unroll
  for (int t = 0; t < 8; t++) acc[t] = {0.f, 0.f, 0.f, 0.f};
  const int rowX = n0 + c16;
#pragma unroll
  for (int ks = 0; ks < 4; ks++) {
    const int cb = ks * 32 + quad * 8;
    const size_t sb = ((size_t)(cb >> 4) * NP) * 16 + (cb & 8);
    f16x8 Ax = *(const f16x8*)(x + sb + (size_t)rowX * 16);
#pragma unroll
    for (int nt = 0; nt < 8; nt++) {
      f16x8 B = *(const f16x8*)(w1 + (size_t)((nt * 4 + ks) * 64 + lane) * 8);
      acc[nt] = MFMA16(Ax, B, acc[nt]);
    }
  }
#pragma unroll
  for (int nt = 0; nt < 8; nt++) {
    const int col = nt * 16 + c16;
    const float bc = b1[col];
#pragma unroll
    for (int r = 0; r < 4; r++)
      sh[lrow + quad * 4 + r][col] = (f16)fmaxf(acc[nt][r] + bc, 0.0f);
  }
  // FC2 (wave-local rows, no barrier needed)
#pragma unroll
  for (int t = 0; t < 8; t++) acc[t] = {0.f, 0.f, 0.f, 0.f};
#pragma unroll
  for (int ks = 0; ks < 4; ks++) {
    f16x8 Ax = *(const f16x8*)&sh[lrow + c16][ks * 32 + quad * 8];
#pragma unroll
    for (int nt = 0; nt < 8; nt++) {
      f16x8 B = *(const f16x8*)(w2 + (size_t)((nt * 4 + ks) * 64 + lane) * 8);
      acc[nt] = MFMA16(Ax, B, acc[nt]);
    }
  }
#pragma unroll
  for (int nt = 0; nt < 8; nt++) {
    const int col = nt * 16 + c16;
    const float bc = b2[col];
#pragma unroll
    for (int r = 0; r < 4; r++)
      sh[lrow + quad * 4 + r][col] = (f16)(acc[nt][r] + bc);
  }
  // FC3 -> out (fp32)
#pragma unroll
  for (int t = 0; t < 8; t++) acc[t] = {0.f, 0.f, 0.f, 0.f};
#pragma unroll
  for (int ks = 0; ks < 4; ks++) {
    f16x8 Ax = *(const f16x8*)&sh[lrow + c16][ks * 32 + quad * 8];
#pragma unroll
    for (int nt = 0; nt < 8; nt++) {
      f16x8 B = *(const f16x8*)(w3 + (size_t)((nt * 4 + ks) * 64 + lane) * 8);
      acc[nt] = MFMA16(Ax, B, acc[nt]);
    }
  }
#pragma unroll
  for (int nt = 0; nt < 8; nt++) {
    const int col = nt * 16 + c16;
    const float bc = b3[col];
#pragma unroll
    for (int r = 0; r < 4; r++) {
      const int node = n0 + quad * 4 + r;
      if (node < NN) out[(size_t)node * CC + col] = acc[nt][r] + bc;
    }
  }
}

extern "C" void kernel_launch(void* const* d_in, const int* in_sizes, int n_in,
                              void* d_out, int out_size, void* d_ws,
                              size_t ws_size, hipStream_t stream) {
  const float* pos = (const float*)d_in[0];
  const int* ei = (const int*)d_in[1];
  const int* src = ei;
  const int* dst = ei + EE;
  auto P = [&](int i) { return (const float*)d_in[i]; };

  // ws: bcur[NBK] | bbase[NBK] | off[NN+2] | bedge[NBK*BCAP] | csr[E] |
  //     wp16 | xa | xb   (~66 MB)
  int* bcur = (int*)d_ws;
  int* bbase = bcur + NBK;
  int* off = bbase + NBK;
  unsigned* bedge = (unsigned*)(off + NN + 2);
  int* csr = (int*)(bedge + (size_t)NBK * BCAP);
  f16* wp16 = (f16*)(csr + EE);
  f16* xa = wp16 + 9 * 16384;
  f16* xb = xa + (size_t)NP * CC;

  f16* agg = (f16*)d_out;  // scratch until the final dense overwrites d_out

  hipMemsetAsync(bcur, 0, NBK * sizeof(int), stream);

  // CSR build: partition -> bucket scan -> per-bucket offsets+fill
  k_part<<<(EE / 4 + 4095) / 4096, 1024, 0, stream>>>(src, dst, bcur, bedge);
  k_bscan<<<1, 1024, 0, stream>>>(bcur, bbase, off);
  k_bfill2<<<NBK, 256, 0, stream>>>(bcur, bbase, bedge, off, csr);

  WPtrs wp;
  const int wsrc[9] = {9, 11, 16, 18, 23, 25, 30, 32, 34};
  for (int i = 0; i < 9; i++) wp.w[i] = P(wsrc[i]);
  k_packw<<<(9 * 16384) / 256, 256, 0, stream>>>(wp, wp16);

  // layer 1 (Cin=3): agg3 fp32 in d_out scratch (1.2 MB)
  k_agg3<<<(NN + 255) / 256, 256, 0, stream>>>(off, csr, pos, (float*)d_out);
  k_node1<<<(NN + 255) / 256, 256, 0, stream>>>(
      (const float*)d_out, pos, P(2), P(3), P(4), P(5), P(6), P(7), P(8), xa);

  const int NB = NP / 64;  // 1563
  // layers 2..4: ping-pong xa -> xb -> xa -> xb
  const f16* xi = xa;
  f16* xo = xb;
  for (int l = 1; l < 4; l++) {
    int base = 2 + 7 * l;
    int mat = (l - 1) * 2;
    k_agg_quad<<<NB * 8, 256, 0, stream>>>(off, csr, xi, agg);
    k_sage_mfma<<<NB, 256, 0, stream>>>(xi, xo, agg,
                                        wp16 + (size_t)mat * 16384,
                                        wp16 + (size_t)(mat + 1) * 16384,
                                        P(base + 1), P(base + 3), P(base + 4),
                                        P(base + 5), P(base + 6));
    const f16* t = xi;
    xi = xo;
    xo = (f16*)t;
  }

  // fused FC head
  k_dense_fused<<<NB, 256, 0, stream>>>(xi, wp16 + (size_t)6 * 16384,
                                        wp16 + (size_t)7 * 16384,
                                        wp16 + (size_t)8 * 16384, P(31), P(33),
                                        P(35), (float*)d_out);
}